// Round 1
// baseline (18426.335 us; speedup 1.0000x reference)
//
#include <hip/hip_runtime.h>
#include <stdint.h>
#include <stddef.h>

// Problem constants
#define B_   32
#define S_   512
#define D_   768
#define H_   1024
#define NF_  50
#define NR_  35
#define NWG  256
#define WGS  256

typedef __attribute__((ext_vector_type(8))) short sh8;   // 8 x bf16 (4 VGPRs) MFMA operand
typedef __attribute__((ext_vector_type(4))) float f4;    // MFMA accumulator
typedef __attribute__((ext_vector_type(2))) float f2v;
typedef __attribute__((ext_vector_type(4))) unsigned int u4x;

__device__ __forceinline__ unsigned short f2bf(float f) {
  unsigned int u = __float_as_uint(f);
  u += 0x7fffu + ((u >> 16) & 1u);      // round-to-nearest-even to bf16
  return (unsigned short)(u >> 16);
}

__device__ __forceinline__ sh8 cvt8(const float* __restrict__ p) {
  f4 av = *(const f4*)p;
  f4 bv = *(const f4*)(p + 4);
  union { sh8 s; unsigned short us[8]; } r;
  r.us[0] = f2bf(av[0]); r.us[1] = f2bf(av[1]); r.us[2] = f2bf(av[2]); r.us[3] = f2bf(av[3]);
  r.us[4] = f2bf(bv[0]); r.us[5] = f2bf(bv[1]); r.us[6] = f2bf(bv[2]); r.us[7] = f2bf(bv[3]);
  return r.s;
}

__device__ __forceinline__ float sigm(float x) { return 1.f / (1.f + __expf(-x)); }

// ---------------------------------------------------------------- init ws
__global__ void init_ws(unsigned int* __restrict__ bar, float* __restrict__ logbuf) {
  const int t = blockIdx.x * blockDim.x + threadIdx.x;
  const int stride = gridDim.x * blockDim.x;
  for (int i = t; i < 3 * 2720; i += stride)
    __hip_atomic_store(&logbuf[i], 0.f, __ATOMIC_RELAXED, __HIP_MEMORY_SCOPE_AGENT);
  if (t == 0) {
    __hip_atomic_store(&bar[0], 0u, __ATOMIC_RELAXED, __HIP_MEMORY_SCOPE_AGENT);
    __hip_atomic_store(&bar[1], 0u, __ATOMIC_RELAXED, __HIP_MEMORY_SCOPE_AGENT);
  }
}

// ------------------------------------------------------- x fp32 -> bf16
__global__ void xcvt(const float* __restrict__ x, unsigned int* __restrict__ xb2, int npairs) {
  const int stride = gridDim.x * blockDim.x;
  for (int i = blockIdx.x * blockDim.x + threadIdx.x; i < npairs; i += stride) {
    f2v v = ((const f2v*)x)[i];
    xb2[i] = (unsigned int)f2bf(v[0]) | ((unsigned int)f2bf(v[1]) << 16);
  }
}

// ---------------------------------------------------------- persistent
// 256 WGs (1 per CU, pinned by LDS usage), 256 threads each.
// WG w<128: F-cell, hidden units [w*8, w*8+8).  WG w>=128: R-cell likewise.
// Per CU gate tile: [32 b x 32 gatecols], gatecols = {g*1024 + j0 + jj}.
// K split over 4 waves; Whh/Wih kept as bf16 MFMA B-fragments in VGPRs.
__global__ __launch_bounds__(WGS, 1) void tpr_persist(
    const float* __restrict__ x, const unsigned short* __restrict__ xbf, int xmode,
    const float* __restrict__ WihF, const float* __restrict__ WhhF,
    const float* __restrict__ bihF, const float* __restrict__ bhhF,
    const float* __restrict__ WihR, const float* __restrict__ WhhR,
    const float* __restrict__ bihR, const float* __restrict__ bhhR,
    const float* __restrict__ WaFw, const float* __restrict__ WaFb,
    const float* __restrict__ WaRw, const float* __restrict__ WaRb,
    const float* __restrict__ Fw, const float* __restrict__ Rw,
    const float* __restrict__ scFp, const float* __restrict__ scRp,
    float* __restrict__ out0, unsigned int* __restrict__ bar,
    float* __restrict__ logbuf)
{
  // LDS (~116 KB -> exactly 1 WG/CU on gfx950's 160 KB)
  __shared__ __align__(16) unsigned short T_lds[32 * 1032]; // padded +8 bf16/row (2-way banks = free)
  __shared__ float part[4][32][33];
  __shared__ float h_lds[256];
  __shared__ float aF_lds[32 * NF_];
  __shared__ float aR_lds[32 * NR_];
  __shared__ float itF[32 * 32];
  __shared__ float itR[32 * 32];
  __shared__ float Fw_l[32 * NF_];
  __shared__ float Rw_l[32 * NR_];
  __shared__ float Wa_l[NF_ * 8];
  __shared__ float bias_l[32];
  __shared__ float bF_l[NF_];
  __shared__ float bR_l[NR_];

  const int wg   = blockIdx.x;
  const int tid  = threadIdx.x;
  const int wave = tid >> 6;
  const int lane = tid & 63;
  const int n16  = lane & 15;
  const int quad = lane >> 4;
  const bool isF = wg < 128;
  const int cuI  = isF ? wg : wg - 128;
  const int j0   = cuI * 8;
  const float* Wih = isF ? WihF : WihR;
  const float* Whh = isF ? WhhF : WhhR;
  const float* bih = isF ? bihF : bihR;
  const float* bhh = isF ? bhhF : bhhR;
  const float* Wa  = isF ? WaFw : WaRw;
  const int NA = isF ? NF_ : NR_;

  // ---- resident weight fragments (VGPRs): wave owns K-quarter
  sh8 whhf[2][8];   // [ntile][kstep of 32] over K=1024/4=256
  sh8 wihf[2][6];   // over K=768/4=192
  #pragma unroll
  for (int nt = 0; nt < 2; ++nt) {
    const int n = nt * 16 + n16;
    const int row = (n >> 3) * 1024 + j0 + (n & 7);   // gate g = n>>3, jj = n&7
    #pragma unroll
    for (int ks = 0; ks < 8; ++ks)
      whhf[nt][ks] = cvt8(Whh + (size_t)row * H_ + wave * 256 + ks * 32 + quad * 8);
    #pragma unroll
    for (int ks = 0; ks < 6; ++ks)
      wihf[nt][ks] = cvt8(Wih + (size_t)row * D_ + wave * 192 + ks * 32 + quad * 8);
  }

  if (tid < 32) {
    const int row = (tid >> 3) * 1024 + j0 + (tid & 7);
    bias_l[tid] = bih[row] + bhh[row];
  }
  for (int i = tid; i < NA * 8; i += WGS)
    Wa_l[i] = Wa[(size_t)(i >> 3) * H_ + j0 + (i & 7)];
  for (int i = tid; i < 32 * NF_; i += WGS) Fw_l[i] = Fw[i];
  for (int i = tid; i < 32 * NR_; i += WGS) Rw_l[i] = Rw[i];
  if (tid < NF_) bF_l[tid] = WaFb[tid];
  if (tid < NR_) bR_l[tid] = WaRb[tid];
  {
    u4x z = {0u, 0u, 0u, 0u};
    for (int i = tid; i < (32 * 1032) / 8; i += WGS) ((u4x*)T_lds)[i] = z;  // T(-1) = 0
  }
  const float sF = scFp[0];
  const float sR = scRp[0];
  float c = 0.f;   // this thread's cell state: (b = tid>>3, jj = tid&7)

  f4 xacc[2][2];
  const f4 fz = {0.f, 0.f, 0.f, 0.f};

  auto xpart = [&](int sx) {   // x_t @ Wih^T slice for step sx (off critical path)
    #pragma unroll
    for (int bt = 0; bt < 2; ++bt)
      #pragma unroll
      for (int nt = 0; nt < 2; ++nt) xacc[bt][nt] = fz;
    #pragma unroll
    for (int ks = 0; ks < 6; ++ks) {
      sh8 xa[2];
      #pragma unroll
      for (int bt = 0; bt < 2; ++bt) {
        const size_t off = ((size_t)(bt * 16 + n16) * S_ + sx) * D_ + wave * 192 + ks * 32 + quad * 8;
        if (xmode == 0) {
          union { u4x u; sh8 s; } t;
          t.u = *(const u4x*)(xbf + off);
          xa[bt] = t.s;
        } else {
          xa[bt] = cvt8(x + off);
        }
      }
      #pragma unroll
      for (int bt = 0; bt < 2; ++bt)
        #pragma unroll
        for (int nt = 0; nt < 2; ++nt)
          xacc[bt][nt] = __builtin_amdgcn_mfma_f32_16x16x32_bf16(xa[bt], wihf[nt][ks], xacc[bt][nt], 0, 0, 0);
    }
  };

  xpart(0);
  __syncthreads();

  unsigned int* cnt = bar;
  unsigned int* flg = bar + 1;
  float* out1 = out0 + (size_t)B_ * S_ * H_;
  float* out2 = out1 + (size_t)B_ * S_ * NF_;

  for (int s = 0; s < S_; ++s) {
    // ---- gates = x-part + T(s-1) @ Whh^T (wave K-quarter partials)
    f4 acc[2][2];
    #pragma unroll
    for (int bt = 0; bt < 2; ++bt)
      #pragma unroll
      for (int nt = 0; nt < 2; ++nt) acc[bt][nt] = xacc[bt][nt];
    if (s > 0) {
      #pragma unroll
      for (int ks = 0; ks < 8; ++ks) {
        sh8 aT[2];
        #pragma unroll
        for (int bt = 0; bt < 2; ++bt)
          aT[bt] = *(const sh8*)&T_lds[(bt * 16 + n16) * 1032 + wave * 256 + ks * 32 + quad * 8];
        #pragma unroll
        for (int bt = 0; bt < 2; ++bt)
          #pragma unroll
          for (int nt = 0; nt < 2; ++nt)
            acc[bt][nt] = __builtin_amdgcn_mfma_f32_16x16x32_bf16(aT[bt], whhf[nt][ks], acc[bt][nt], 0, 0, 0);
      }
    }
    #pragma unroll
    for (int bt = 0; bt < 2; ++bt)
      #pragma unroll
      for (int nt = 0; nt < 2; ++nt)
        #pragma unroll
        for (int r = 0; r < 4; ++r)
          part[wave][bt * 16 + quad * 4 + r][nt * 16 + n16] = acc[bt][nt][r];  // D: row=quad*4+reg, col=lane&15
    __syncthreads();

    // ---- cross-wave reduce -> gate nonlinearity -> c,h (thread = (b,jj))
    {
      const int b = tid >> 3, jj = tid & 7;
      float G[4];
      #pragma unroll
      for (int gi = 0; gi < 4; ++gi) {
        const int n = gi * 8 + jj;
        G[gi] = bias_l[n] + part[0][b][n] + part[1][b][n] + part[2][b][n] + part[3][b][n];
      }
      const float ig = sigm(G[0]);
      const float fg = sigm(G[1]);
      const float gg = tanhf(G[2]);
      const float og = sigm(G[3]);
      c = fg * c + ig * gg;
      h_lds[tid] = og * tanhf(c);
    }
    __syncthreads();

    // ---- partial attention logits -> device-scope atomics (buffer s%3)
    float* lb = logbuf + (s % 3) * 2720;
    {
      float* lbt = lb + (isF ? 0 : 1600);
      for (int i = tid; i < NA * 32; i += WGS) {
        const int b = i / NA, n = i - b * NA;
        float v = 0.f;
        #pragma unroll
        for (int jj = 0; jj < 8; ++jj) v += h_lds[b * 8 + jj] * Wa_l[n * 8 + jj];
        atomicAdd(&lbt[b * NA + n], v);
      }
    }
    // zero the buffer for step s+1 (untouched this window: reads hit (s-1)%3, adds hit s%3)
    if (wg == NWG - 1) {
      float* zb = logbuf + ((s + 1) % 3) * 2720;
      for (int i = tid; i < 2720; i += WGS)
        __hip_atomic_store(&zb[i], 0.f, __ATOMIC_RELAXED, __HIP_MEMORY_SCOPE_AGENT);
    }
    __syncthreads();   // drains vmcnt: all this WG's atomics committed before arrival

    // ---- global barrier: arrive
    if (tid == 0) {
      const unsigned int old = __hip_atomic_fetch_add(cnt, 1u, __ATOMIC_ACQ_REL, __HIP_MEMORY_SCOPE_AGENT);
      if (old == NWG - 1) {
        __hip_atomic_store(cnt, 0u, __ATOMIC_RELAXED, __HIP_MEMORY_SCOPE_AGENT);
        __hip_atomic_store(flg, (unsigned int)(s + 1), __ATOMIC_RELEASE, __HIP_MEMORY_SCOPE_AGENT);
      }
    }
    // overlap the barrier wait with next step's x-projection
    if (s + 1 < S_) xpart(s + 1);
    if (tid == 0) {
      while (__hip_atomic_load(flg, __ATOMIC_ACQUIRE, __HIP_MEMORY_SCOPE_AGENT) < (unsigned int)(s + 1))
        __builtin_amdgcn_s_sleep(1);
    }
    __syncthreads();
    __threadfence();

    // ---- read reduced logits (LLC-coherent atomic loads) + attention bias
    for (int i = tid; i < 32 * NF_; i += WGS)
      aF_lds[i] = __hip_atomic_load(&lb[i], __ATOMIC_RELAXED, __HIP_MEMORY_SCOPE_AGENT) + bF_l[i % NF_];
    for (int i = tid; i < 32 * NR_; i += WGS)
      aR_lds[i] = __hip_atomic_load(&lb[1600 + i], __ATOMIC_RELAXED, __HIP_MEMORY_SCOPE_AGENT) + bR_l[i % NR_];
    __syncthreads();

    // ---- softmax (wave0: aF rows, wave1: aR rows) — identical on every CU
    if (wave == 0 && lane < 32) {
      float* r = &aF_lds[lane * NF_];
      float ssum = 0.f;
      for (int n = 0; n < NF_; ++n) { const float e = __expf(r[n]); r[n] = e; ssum += e; }
      const float rin = 1.f / ssum;
      for (int n = 0; n < NF_; ++n) r[n] *= rin;
    } else if (wave == 1 && lane < 32) {
      float* r = &aR_lds[lane * NR_];
      float ssum = 0.f;
      for (int n = 0; n < NR_; ++n) { const float e = __expf(r[n]); r[n] = e; ssum += e; }
      const float rin = 1.f / ssum;
      for (int n = 0; n < NR_; ++n) r[n] *= rin;
    }
    __syncthreads();

    // ---- items (fp32, redundant per CU)
    {
      const int b = tid >> 3, d0 = (tid & 7) * 4;
      #pragma unroll
      for (int k = 0; k < 4; ++k) {
        const int ds = d0 + k;
        float vF = 0.f, vR = 0.f;
        for (int n = 0; n < NF_; ++n) vF += aF_lds[b * NF_ + n] * Fw_l[ds * NF_ + n];
        for (int n = 0; n < NR_; ++n) vR += aR_lds[b * NR_ + n] * Rw_l[ds * NR_ + n];
        itF[b * 32 + ds] = sF * vF;
        itR[b * 32 + ds] = sR * vR;
      }
    }
    __syncthreads();

    // ---- T(s) = outer(itemF,itemR) -> bf16 LDS for next step's MFMA A-operand
    {
      const int b = tid & 31;
      const int dsb0 = (tid >> 5) * 4;
      #pragma unroll
      for (int dsb = 0; dsb < 4; ++dsb) {
        const int ds = dsb0 + dsb;
        const float fv = itF[b * 32 + ds];
        union { unsigned short us[32]; u4x v[4]; } tmp;
        #pragma unroll
        for (int dr = 0; dr < 32; ++dr) tmp.us[dr] = f2bf(fv * itR[b * 32 + dr]);
        #pragma unroll
        for (int q = 0; q < 4; ++q)
          *(u4x*)&T_lds[b * 1032 + ds * 32 + q * 8] = tmp.v[q];
      }
    }

    // ---- designated output writers (all CUs hold identical values)
    if (wg == 254) {
      for (int i = tid; i < 32 * NF_; i += WGS) {
        const int b = i / NF_, n = i - b * NF_;
        out1[((size_t)b * S_ + s) * NF_ + n] = aF_lds[i];
      }
    } else if (wg == 253) {
      for (int i = tid; i < 32 * NR_; i += WGS) {
        const int b = i / NR_, n = i - b * NR_;
        out2[((size_t)b * S_ + s) * NR_ + n] = aR_lds[i];
      }
    } else if (wg >= 160 && wg < 192) {
      const int b = wg - 160;
      const int ds = tid >> 3, dr0 = (tid & 7) * 4;
      f4 v;
      #pragma unroll
      for (int q = 0; q < 4; ++q) v[q] = itF[b * 32 + ds] * itR[b * 32 + dr0 + q];
      *(f4*)&out0[((size_t)b * S_ + s) * H_ + tid * 4] = v;
    }
    __syncthreads();   // T_lds ready before next iteration's MFMA reads
  }
}

// ------------------------------------------------------------- launcher
extern "C" void kernel_launch(void* const* d_in, const int* in_sizes, int n_in,
                              void* d_out, int out_size, void* d_ws, size_t ws_size,
                              hipStream_t stream) {
  (void)in_sizes; (void)n_in; (void)out_size;
  const float* x    = (const float*)d_in[0];
  const float* WihF = (const float*)d_in[1];
  const float* WhhF = (const float*)d_in[2];
  const float* bihF = (const float*)d_in[3];
  const float* bhhF = (const float*)d_in[4];
  const float* WihR = (const float*)d_in[5];
  const float* WhhR = (const float*)d_in[6];
  const float* bihR = (const float*)d_in[7];
  const float* bhhR = (const float*)d_in[8];
  const float* WaFw = (const float*)d_in[9];
  const float* WaFb = (const float*)d_in[10];
  const float* WaRw = (const float*)d_in[11];
  const float* WaRb = (const float*)d_in[12];
  const float* Fw   = (const float*)d_in[13];
  const float* Rw   = (const float*)d_in[14];
  const float* scF  = (const float*)d_in[15];
  const float* scR  = (const float*)d_in[16];

  unsigned int* bar = (unsigned int*)d_ws;
  float* logbuf = (float*)((char*)d_ws + 256);
  unsigned short* xbf = (unsigned short*)((char*)d_ws + 65536);
  const size_t need = 65536 + (size_t)B_ * S_ * D_ * 2;
  const int xmode = (ws_size >= need) ? 0 : 1;

  init_ws<<<8, 256, 0, stream>>>(bar, logbuf);
  if (xmode == 0)
    xcvt<<<2048, 256, 0, stream>>>(x, (unsigned int*)xbf, (B_ * S_ * D_) / 2);
  tpr_persist<<<NWG, WGS, 0, stream>>>(x, xbf, xmode,
      WihF, WhhF, bihF, bhhF, WihR, WhhR, bihR, bhhR,
      WaFw, WaFb, WaRw, WaRb, Fw, Rw, scF, scR,
      (float*)d_out, bar, logbuf);
}

// Round 2
// 16164.728 us; speedup vs baseline: 1.1399x; 1.1399x over previous
//
#include <hip/hip_runtime.h>
#include <stdint.h>
#include <stddef.h>

// Problem constants
#define B_   32
#define S_   512
#define D_   768
#define H_   1024
#define NF_  50
#define NR_  35
#define NWG  128      // 64 WGs per cell, 16 hidden units each
#define WGS  256

typedef __attribute__((ext_vector_type(8))) short sh8;   // 8 x bf16 MFMA operand
typedef __attribute__((ext_vector_type(4))) float f4;
typedef __attribute__((ext_vector_type(2))) float f2v;
typedef __attribute__((ext_vector_type(4))) unsigned int u4x;

__device__ __forceinline__ unsigned short f2bf(float f) {
  unsigned int u = __float_as_uint(f);
  u += 0x7fffu + ((u >> 16) & 1u);
  return (unsigned short)(u >> 16);
}

__device__ __forceinline__ sh8 cvt8(const float* __restrict__ p) {
  f4 av = *(const f4*)p;
  f4 bv = *(const f4*)(p + 4);
  union { sh8 s; unsigned short us[8]; } r;
  r.us[0] = f2bf(av[0]); r.us[1] = f2bf(av[1]); r.us[2] = f2bf(av[2]); r.us[3] = f2bf(av[3]);
  r.us[4] = f2bf(bv[0]); r.us[5] = f2bf(bv[1]); r.us[6] = f2bf(bv[2]); r.us[7] = f2bf(bv[3]);
  return r.s;
}

__device__ __forceinline__ float sigm(float x) { return 1.f / (1.f + __expf(-x)); }

// ws layout (bytes):
//   [0, 16384)        pflag[128]  : dword at wg*32 dwords  (1 line each)
//   [16384, 24576)    rflag[64]   : dword at job*32 dwords (1 line each)
//   [24576, 40960)    itBuf[2][64][32] floats  (row = 128 B = 1 line)
//   [65536, 65536+2*128*1600*4)   pf partial logits
//   [1703936, +B*S*D*2)           xbf
#define PF_OFF   65536
#define XBF_OFF  1703936

// ---------------------------------------------------------------- init ws
__global__ void init_ws(unsigned int* __restrict__ flags) {
  const int t = blockIdx.x * blockDim.x + threadIdx.x;
  const int stride = gridDim.x * blockDim.x;
  for (int i = t; i < 6144; i += stride)   // 24576 B of flags
    __hip_atomic_store(&flags[i], 0u, __ATOMIC_RELAXED, __HIP_MEMORY_SCOPE_AGENT);
}

// ------------------------------------------------------- x fp32 -> bf16
__global__ void xcvt(const float* __restrict__ x, unsigned int* __restrict__ xb2, int npairs) {
  const int stride = gridDim.x * blockDim.x;
  for (int i = blockIdx.x * blockDim.x + threadIdx.x; i < npairs; i += stride) {
    f2v v = ((const f2v*)x)[i];
    xb2[i] = (unsigned int)f2bf(v[0]) | ((unsigned int)f2bf(v[1]) << 16);
  }
}

// ---------------------------------------------------------- persistent
__global__ __launch_bounds__(WGS, 1) void tpr_persist(
    const float* __restrict__ x, const unsigned short* __restrict__ xbf, int xmode,
    const float* __restrict__ WihF, const float* __restrict__ WhhF,
    const float* __restrict__ bihF, const float* __restrict__ bhhF,
    const float* __restrict__ WihR, const float* __restrict__ WhhR,
    const float* __restrict__ bihR, const float* __restrict__ bhhR,
    const float* __restrict__ WaFw, const float* __restrict__ WaFb,
    const float* __restrict__ WaRw, const float* __restrict__ WaRb,
    const float* __restrict__ Fw, const float* __restrict__ Rw,
    const float* __restrict__ scFp, const float* __restrict__ scRp,
    float* __restrict__ out0, unsigned char* __restrict__ ws)
{
  __shared__ __align__(16) unsigned short T_lds[32 * 1032];  // 66048 B
  __shared__ float part[4][32 * 69];                         // 35328 B, stride-69 pad
  __shared__ float h_lds[32 * 16];
  __shared__ float itF_l[32 * 33];
  __shared__ float itR_l[32 * 33];
  __shared__ float Fw_l[32 * NF_];
  __shared__ float Rw_l[32 * NR_];
  __shared__ float Wa_l[NF_ * 17];
  __shared__ float arow[64];
  __shared__ float bias_l[64];
  __shared__ float bF_l[NF_];
  __shared__ float bR_l[NR_];

  const int wg   = blockIdx.x;
  const int tid  = threadIdx.x;
  const int wave = tid >> 6;
  const int lane = tid & 63;
  const int n16  = lane & 15;
  const int quad = lane >> 4;
  const bool isF = wg < 64;
  const int j0   = (wg & 63) * 16;
  const float* Wih = isF ? WihF : WihR;
  const float* Whh = isF ? WhhF : WhhR;
  const float* bih = isF ? bihF : bihR;
  const float* bhh = isF ? bhhF : bhhR;
  const float* Wa  = isF ? WaFw : WaRw;
  const int NA = isF ? NF_ : NR_;

  unsigned int* pflag = (unsigned int*)ws;
  unsigned int* rflag = (unsigned int*)(ws + 16384);
  float* itBuf = (float*)(ws + 24576);
  float* pf    = (float*)(ws + PF_OFF);

  // ---- resident weight fragments: wave owns K-quarter; 4 gate n-tiles
  sh8 whhf[4][8];
  sh8 wihf[4][6];
  #pragma unroll
  for (int g = 0; g < 4; ++g) {
    const int row = g * 1024 + j0 + n16;
    #pragma unroll
    for (int ks = 0; ks < 8; ++ks)
      whhf[g][ks] = cvt8(Whh + (size_t)row * H_ + wave * 256 + ks * 32 + quad * 8);
    #pragma unroll
    for (int ks = 0; ks < 6; ++ks)
      wihf[g][ks] = cvt8(Wih + (size_t)row * D_ + wave * 192 + ks * 32 + quad * 8);
  }

  if (tid < 64) {
    const int row = (tid >> 4) * 1024 + j0 + (tid & 15);
    bias_l[tid] = bih[row] + bhh[row];
  }
  for (int i = tid; i < NA * 16; i += WGS)
    Wa_l[(i >> 4) * 17 + (i & 15)] = Wa[(size_t)(i >> 4) * H_ + j0 + (i & 15)];
  for (int i = tid; i < 32 * NF_; i += WGS) Fw_l[i] = Fw[i];
  for (int i = tid; i < 32 * NR_; i += WGS) Rw_l[i] = Rw[i];
  if (tid < NF_) bF_l[tid] = WaFb[tid];
  if (tid < NR_) bR_l[tid] = WaRb[tid];
  {
    u4x z = {0u, 0u, 0u, 0u};
    for (int i = tid; i < (32 * 1032) / 8; i += WGS) ((u4x*)T_lds)[i] = z;
  }
  const float sF = scFp[0];
  const float sR = scRp[0];
  float c0 = 0.f, c1 = 0.f;   // cell state for (b=tid>>3, jj=(tid&7)*2 +0/1)

  f4 xacc[2][4];
  const f4 fz = {0.f, 0.f, 0.f, 0.f};

  auto xpart = [&](int sx) {
    #pragma unroll
    for (int bt = 0; bt < 2; ++bt)
      #pragma unroll
      for (int g = 0; g < 4; ++g) xacc[bt][g] = fz;
    #pragma unroll
    for (int ks = 0; ks < 6; ++ks) {
      sh8 xa[2];
      #pragma unroll
      for (int bt = 0; bt < 2; ++bt) {
        const size_t off = ((size_t)(bt * 16 + n16) * S_ + sx) * D_ + wave * 192 + ks * 32 + quad * 8;
        if (xmode == 0) {
          union { u4x u; sh8 s; } t;
          t.u = *(const u4x*)(xbf + off);
          xa[bt] = t.s;
        } else {
          xa[bt] = cvt8(x + off);
        }
      }
      #pragma unroll
      for (int bt = 0; bt < 2; ++bt)
        #pragma unroll
        for (int g = 0; g < 4; ++g)
          xacc[bt][g] = __builtin_amdgcn_mfma_f32_16x16x32_bf16(xa[bt], wihf[g][ks], xacc[bt][g], 0, 0, 0);
    }
  };

  xpart(0);
  __syncthreads();

  float* out1 = out0 + (size_t)B_ * S_ * H_;
  float* out2 = out1 + (size_t)B_ * S_ * NF_;

  // reducer roles: F: wg 0..31 -> batch wg ; R: wg 96..127 -> batch wg-96
  const bool isRed = (wg < 32) || (wg >= 96);
  const int  redB  = (wg < 32) ? wg : wg - 96;
  const bool redF  = (wg < 32);

  for (int s = 0; s < S_; ++s) {
    const int buf = s & 1;

    // ---- 1. gates = xacc + T(s-1) @ Whh^T
    f4 acc[2][4];
    #pragma unroll
    for (int bt = 0; bt < 2; ++bt)
      #pragma unroll
      for (int g = 0; g < 4; ++g) acc[bt][g] = xacc[bt][g];
    if (s > 0) {
      #pragma unroll
      for (int ks = 0; ks < 8; ++ks) {
        sh8 aT[2];
        #pragma unroll
        for (int bt = 0; bt < 2; ++bt)
          aT[bt] = *(const sh8*)&T_lds[(bt * 16 + n16) * 1032 + wave * 256 + ks * 32 + quad * 8];
        #pragma unroll
        for (int bt = 0; bt < 2; ++bt)
          #pragma unroll
          for (int g = 0; g < 4; ++g)
            acc[bt][g] = __builtin_amdgcn_mfma_f32_16x16x32_bf16(aT[bt], whhf[g][ks], acc[bt][g], 0, 0, 0);
      }
    }
    #pragma unroll
    for (int bt = 0; bt < 2; ++bt)
      #pragma unroll
      for (int g = 0; g < 4; ++g)
        #pragma unroll
        for (int r = 0; r < 4; ++r)
          part[wave][(bt * 16 + quad * 4 + r) * 69 + g * 16 + n16] = acc[bt][g][r];
    __syncthreads();

    // ---- 2. cross-wave reduce -> nonlinearity -> c,h   (thread: b=tid>>3, jj pair)
    {
      const int b = tid >> 3;
      const int jb = (tid & 7) * 2;
      #pragma unroll
      for (int u = 0; u < 2; ++u) {
        const int jj = jb + u;
        float G[4];
        #pragma unroll
        for (int g = 0; g < 4; ++g) {
          const int n = g * 16 + jj;
          G[g] = bias_l[n] + part[0][b * 69 + n] + part[1][b * 69 + n]
                           + part[2][b * 69 + n] + part[3][b * 69 + n];
        }
        const float ig = sigm(G[0]);
        const float fg = sigm(G[1]);
        const float gg = tanhf(G[2]);
        const float og = sigm(G[3]);
        float& c = u ? c1 : c0;
        c = fg * c + ig * gg;
        h_lds[b * 16 + jj] = og * tanhf(c);
      }
    }
    __syncthreads();

    // ---- 3. partial logits -> private pf slice (sc1 write-through, coalesced)
    {
      float* dst = pf + ((size_t)buf * NWG + wg) * 1600;
      for (int i = tid; i < NA * 32; i += WGS) {
        const int b = i / NA, n = i - b * NA;
        float v = 0.f;
        #pragma unroll
        for (int jj = 0; jj < 16; ++jj) v += h_lds[b * 16 + jj] * Wa_l[n * 17 + jj];
        __hip_atomic_store(&dst[i], v, __ATOMIC_RELAXED, __HIP_MEMORY_SCOPE_AGENT);
      }
    }
    __syncthreads();   // all waves drain vmcnt before flag
    if (tid == 0)
      __hip_atomic_store(&pflag[wg * 32], (unsigned int)(s + 1), __ATOMIC_RELEASE, __HIP_MEMORY_SCOPE_AGENT);

    // ---- 4. reducer wave0: reduce 64 partials -> softmax -> items -> publish
    if (isRed && wave == 0) {
      const int cellbase = redF ? 0 : 64;
      // poll the 64 writer flags of my cell (each on its own line)
      for (;;) {
        const unsigned int v = __hip_atomic_load(&pflag[(cellbase + lane) * 32],
                                                 __ATOMIC_RELAXED, __HIP_MEMORY_SCOPE_AGENT);
        if (__ballot(v >= (unsigned int)(s + 1)) == ~0ull) break;
        __builtin_amdgcn_s_sleep(2);
      }
      __builtin_amdgcn_fence(__ATOMIC_ACQUIRE, "agent");
      const int NAr = redF ? NF_ : NR_;
      const int n = (lane < NAr) ? lane : NAr - 1;
      const float* pfb = pf + ((size_t)buf * NWG + cellbase) * 1600 + redB * NAr + n;
      float v = 0.f;
      #pragma unroll 8
      for (int w = 0; w < 64; ++w) v += pfb[(size_t)w * 1600];
      const float* bA = redF ? bF_l : bR_l;
      float e = (lane < NAr) ? __expf(v + bA[n]) : 0.f;
      float ssum = e;
      #pragma unroll
      for (int off = 1; off < 64; off <<= 1) ssum += __shfl_xor(ssum, off, 64);
      const float a = e / ssum;
      if (lane < NAr) {
        arow[lane] = a;
        float* outA = redF ? out1 : out2;
        outA[((size_t)redB * S_ + s) * NAr + lane] = a;   // plain store
      }
      if (lane < 32) {
        const float* WL = redF ? Fw_l : Rw_l;
        const float sc = redF ? sF : sR;
        float it = 0.f;
        for (int k = 0; k < NAr; ++k) it += arow[k] * WL[lane * NAr + k];
        it *= sc;
        __hip_atomic_store(&itBuf[((size_t)buf * 64 + (redF ? 0 : 32) + redB) * 32 + lane],
                           it, __ATOMIC_RELAXED, __HIP_MEMORY_SCOPE_AGENT);
      }
      if (lane == 0)
        __hip_atomic_store(&rflag[((redF ? 0 : 32) + redB) * 32], (unsigned int)(s + 1),
                           __ATOMIC_RELEASE, __HIP_MEMORY_SCOPE_AGENT);
    }

    // ---- 5. overlap: next step's x-projection
    if (s + 1 < S_) xpart(s + 1);

    // ---- 6. wait for all 64 items rows
    if (wave == 0) {
      for (;;) {
        const unsigned int v = __hip_atomic_load(&rflag[lane * 32],
                                                 __ATOMIC_RELAXED, __HIP_MEMORY_SCOPE_AGENT);
        if (__ballot(v >= (unsigned int)(s + 1)) == ~0ull) break;
        __builtin_amdgcn_s_sleep(2);
      }
    }
    __syncthreads();
    __builtin_amdgcn_fence(__ATOMIC_ACQUIRE, "agent");

    // ---- 7. read itemF/itemR (plain coalesced loads), stage to LDS
    {
      const float* src = itBuf + (size_t)buf * 2048;
      for (int i = tid; i < 2048; i += WGS) {
        const int row = i >> 5, dcol = i & 31;
        const float v = src[i];
        if (row < 32) itF_l[row * 33 + dcol] = v;
        else          itR_l[(row - 32) * 33 + dcol] = v;
      }
    }
    __syncthreads();

    // ---- 8. T(s) = outer(itemF,itemR) -> bf16 LDS ; out0 by wg 32..63
    {
      const int b = tid & 31;
      const int ds0 = (tid >> 5) * 4;
      #pragma unroll
      for (int dsb = 0; dsb < 4; ++dsb) {
        const int ds = ds0 + dsb;
        const float fv = itF_l[b * 33 + ds];
        union { unsigned short us[32]; u4x v[4]; } tmp;
        #pragma unroll
        for (int dr = 0; dr < 32; ++dr) tmp.us[dr] = f2bf(fv * itR_l[b * 33 + dr]);
        #pragma unroll
        for (int q = 0; q < 4; ++q)
          *(u4x*)&T_lds[b * 1032 + ds * 32 + q * 8] = tmp.v[q];
      }
    }
    if (wg >= 32 && wg < 64) {
      const int b = wg - 32;
      const int ds = tid >> 3, dr0 = (tid & 7) * 4;
      f4 v;
      #pragma unroll
      for (int q = 0; q < 4; ++q) v[q] = itF_l[b * 33 + ds] * itR_l[b * 33 + dr0 + q];
      *(f4*)&out0[((size_t)b * S_ + s) * H_ + tid * 4] = v;
    }
    __syncthreads();
  }
}

// ------------------------------------------------------------- launcher
extern "C" void kernel_launch(void* const* d_in, const int* in_sizes, int n_in,
                              void* d_out, int out_size, void* d_ws, size_t ws_size,
                              hipStream_t stream) {
  (void)in_sizes; (void)n_in; (void)out_size;
  const float* x    = (const float*)d_in[0];
  const float* WihF = (const float*)d_in[1];
  const float* WhhF = (const float*)d_in[2];
  const float* bihF = (const float*)d_in[3];
  const float* bhhF = (const float*)d_in[4];
  const float* WihR = (const float*)d_in[5];
  const float* WhhR = (const float*)d_in[6];
  const float* bihR = (const float*)d_in[7];
  const float* bhhR = (const float*)d_in[8];
  const float* WaFw = (const float*)d_in[9];
  const float* WaFb = (const float*)d_in[10];
  const float* WaRw = (const float*)d_in[11];
  const float* WaRb = (const float*)d_in[12];
  const float* Fw   = (const float*)d_in[13];
  const float* Rw   = (const float*)d_in[14];
  const float* scF  = (const float*)d_in[15];
  const float* scR  = (const float*)d_in[16];

  unsigned char* ws = (unsigned char*)d_ws;
  unsigned short* xbf = (unsigned short*)(ws + XBF_OFF);
  const size_t need = (size_t)XBF_OFF + (size_t)B_ * S_ * D_ * 2;
  const int xmode = (ws_size >= need) ? 0 : 1;

  init_ws<<<8, 256, 0, stream>>>((unsigned int*)ws);
  if (xmode == 0)
    xcvt<<<2048, 256, 0, stream>>>(x, (unsigned int*)xbf, (B_ * S_ * D_) / 2);
  tpr_persist<<<NWG, WGS, 0, stream>>>(x, xbf, xmode,
      WihF, WhhF, bihF, bhhF, WihR, WhhR, bihR, bhhR,
      WaFw, WaFb, WaRw, WaRb, Fw, Rw, scF, scR,
      (float*)d_out, ws);
}

// Round 3
// 11829.197 us; speedup vs baseline: 1.5577x; 1.3665x over previous
//
#include <hip/hip_runtime.h>
#include <stdint.h>
#include <stddef.h>

// Problem constants
#define B_   32
#define S_   512
#define D_   768
#define H_   1024
#define NF_  50
#define NR_  35
#define NWG  128      // 64 WGs per cell, 16 hidden units each
#define WGS  256

// ws layout (bytes):
//   [0,128)      cnt1F (dword 0)
//   [128,256)    cnt1R (dword 32)
//   [256,384)    cnt2  (dword 64)
//   [24576, +16384)  itBuf[2][64][32] floats (row = 128 B line)
//   [65536, ...)     pf partial logits, transposed [buf][cell][b][w][n]
//   [1703936, ...)   xbf
#define PF_OFF    65536
#define XBF_OFF   1703936
#define PF_F_SZ   102400            // 32*64*50 floats
#define PF_STEP   174080            // + 32*64*35 floats

typedef __attribute__((ext_vector_type(8))) short sh8;   // 8 x bf16 MFMA operand
typedef __attribute__((ext_vector_type(4))) float f4;
typedef __attribute__((ext_vector_type(2))) float f2v;
typedef __attribute__((ext_vector_type(4))) unsigned int u4x;

__device__ __forceinline__ unsigned short f2bf(float f) {
  unsigned int u = __float_as_uint(f);
  u += 0x7fffu + ((u >> 16) & 1u);
  return (unsigned short)(u >> 16);
}

__device__ __forceinline__ sh8 cvt8(const float* __restrict__ p) {
  f4 av = *(const f4*)p;
  f4 bv = *(const f4*)(p + 4);
  union { sh8 s; unsigned short us[8]; } r;
  r.us[0] = f2bf(av[0]); r.us[1] = f2bf(av[1]); r.us[2] = f2bf(av[2]); r.us[3] = f2bf(av[3]);
  r.us[4] = f2bf(bv[0]); r.us[5] = f2bf(bv[1]); r.us[6] = f2bf(bv[2]); r.us[7] = f2bf(bv[3]);
  return r.s;
}

__device__ __forceinline__ float sigm(float x) { return 1.f / (1.f + __expf(-x)); }

// ---------------------------------------------------------------- init ws
__global__ void init_ws(unsigned int* __restrict__ flags) {
  const int t = blockIdx.x * blockDim.x + threadIdx.x;
  const int stride = gridDim.x * blockDim.x;
  for (int i = t; i < 6144; i += stride)
    __hip_atomic_store(&flags[i], 0u, __ATOMIC_RELAXED, __HIP_MEMORY_SCOPE_AGENT);
}

// ------------------------------------------------------- x fp32 -> bf16
__global__ void xcvt(const float* __restrict__ x, unsigned int* __restrict__ xb2, int npairs) {
  const int stride = gridDim.x * blockDim.x;
  for (int i = blockIdx.x * blockDim.x + threadIdx.x; i < npairs; i += stride) {
    f2v v = ((const f2v*)x)[i];
    xb2[i] = (unsigned int)f2bf(v[0]) | ((unsigned int)f2bf(v[1]) << 16);
  }
}

// ---------------------------------------------------------- persistent
__global__ __launch_bounds__(WGS, 1) void tpr_persist(
    const float* __restrict__ x, const unsigned short* __restrict__ xbf, int xmode,
    const float* __restrict__ WihF, const float* __restrict__ WhhF,
    const float* __restrict__ bihF, const float* __restrict__ bhhF,
    const float* __restrict__ WihR, const float* __restrict__ WhhR,
    const float* __restrict__ bihR, const float* __restrict__ bhhR,
    const float* __restrict__ WaFw, const float* __restrict__ WaFb,
    const float* __restrict__ WaRw, const float* __restrict__ WaRb,
    const float* __restrict__ Fw, const float* __restrict__ Rw,
    const float* __restrict__ scFp, const float* __restrict__ scRp,
    float* __restrict__ out0, unsigned char* __restrict__ ws)
{
  __shared__ __align__(16) unsigned short T_lds[32 * 1032];  // 66048 B
  __shared__ __align__(16) float part[4][32 * 69];           // 35328 B; reused as pf stage
  __shared__ float h_lds[32 * 16];
  __shared__ float itF_l[32 * 33];
  __shared__ float itR_l[32 * 33];
  __shared__ float Fw_l[32 * NF_];
  __shared__ float Rw_l[32 * NR_];
  __shared__ float Wa_l[NF_ * 17];
  __shared__ float arow[64];
  __shared__ float bias_l[64];
  __shared__ float bF_l[NF_];
  __shared__ float bR_l[NR_];

  const int wg   = blockIdx.x;
  const int tid  = threadIdx.x;
  const int wave = tid >> 6;
  const int lane = tid & 63;
  const int n16  = lane & 15;
  const int quad = lane >> 4;
  const bool isF = wg < 64;
  const int wIdx = wg & 63;            // writer index within cell
  const int j0   = wIdx * 16;
  const float* Wih = isF ? WihF : WihR;
  const float* Whh = isF ? WhhF : WhhR;
  const float* bih = isF ? bihF : bihR;
  const float* bhh = isF ? bhhF : bhhR;
  const float* Wa  = isF ? WaFw : WaRw;
  const int NA = isF ? NF_ : NR_;

  unsigned int* cnt1F = (unsigned int*)ws;
  unsigned int* cnt1R = (unsigned int*)(ws + 128);
  unsigned int* cnt2  = (unsigned int*)(ws + 256);
  float* itBuf = (float*)(ws + 24576);
  float* pf    = (float*)(ws + PF_OFF);

  // ---- resident weight fragments: wave owns K-quarter; 4 gate n-tiles
  sh8 whhf[4][8];
  sh8 wihf[4][6];
  #pragma unroll
  for (int g = 0; g < 4; ++g) {
    const int row = g * 1024 + j0 + n16;
    #pragma unroll
    for (int ks = 0; ks < 8; ++ks)
      whhf[g][ks] = cvt8(Whh + (size_t)row * H_ + wave * 256 + ks * 32 + quad * 8);
    #pragma unroll
    for (int ks = 0; ks < 6; ++ks)
      wihf[g][ks] = cvt8(Wih + (size_t)row * D_ + wave * 192 + ks * 32 + quad * 8);
  }

  if (tid < 64) {
    const int row = (tid >> 4) * 1024 + j0 + (tid & 15);
    bias_l[tid] = bih[row] + bhh[row];
  }
  for (int i = tid; i < NA * 16; i += WGS)
    Wa_l[(i >> 4) * 17 + (i & 15)] = Wa[(size_t)(i >> 4) * H_ + j0 + (i & 15)];
  for (int i = tid; i < 32 * NF_; i += WGS) Fw_l[i] = Fw[i];
  for (int i = tid; i < 32 * NR_; i += WGS) Rw_l[i] = Rw[i];
  if (tid < NF_) bF_l[tid] = WaFb[tid];
  if (tid < NR_) bR_l[tid] = WaRb[tid];
  {
    u4x z = {0u, 0u, 0u, 0u};
    for (int i = tid; i < (32 * 1032) / 8; i += WGS) ((u4x*)T_lds)[i] = z;
  }
  const float sF = scFp[0];
  const float sR = scRp[0];
  float c0 = 0.f, c1 = 0.f;

  f4 xacc[2][4];
  const f4 fz = {0.f, 0.f, 0.f, 0.f};

  auto xpart = [&](int sx) {
    #pragma unroll
    for (int bt = 0; bt < 2; ++bt)
      #pragma unroll
      for (int g = 0; g < 4; ++g) xacc[bt][g] = fz;
    #pragma unroll
    for (int ks = 0; ks < 6; ++ks) {
      sh8 xa[2];
      #pragma unroll
      for (int bt = 0; bt < 2; ++bt) {
        const size_t off = ((size_t)(bt * 16 + n16) * S_ + sx) * D_ + wave * 192 + ks * 32 + quad * 8;
        if (xmode == 0) {
          union { u4x u; sh8 s; } t;
          t.u = *(const u4x*)(xbf + off);
          xa[bt] = t.s;
        } else {
          xa[bt] = cvt8(x + off);
        }
      }
      #pragma unroll
      for (int bt = 0; bt < 2; ++bt)
        #pragma unroll
        for (int g = 0; g < 4; ++g)
          xacc[bt][g] = __builtin_amdgcn_mfma_f32_16x16x32_bf16(xa[bt], wihf[g][ks], xacc[bt][g], 0, 0, 0);
    }
  };

  xpart(0);
  __syncthreads();

  float* out1 = out0 + (size_t)B_ * S_ * H_;
  float* out2 = out1 + (size_t)B_ * S_ * NF_;

  // reducers: F on wg 0..31 (batch=wg), R on wg 96..127 (batch=wg-96)
  const bool isRed = (wg < 32) || (wg >= 96);
  const int  redB  = (wg < 32) ? wg : wg - 96;
  const bool redF  = (wg < 32);

  for (int s = 0; s < S_; ++s) {
    const int buf = s & 1;

    // ---- 1. gates = xacc + T(s-1) @ Whh^T
    f4 acc[2][4];
    #pragma unroll
    for (int bt = 0; bt < 2; ++bt)
      #pragma unroll
      for (int g = 0; g < 4; ++g) acc[bt][g] = xacc[bt][g];
    if (s > 0) {
      #pragma unroll
      for (int ks = 0; ks < 8; ++ks) {
        sh8 aT[2];
        #pragma unroll
        for (int bt = 0; bt < 2; ++bt)
          aT[bt] = *(const sh8*)&T_lds[(bt * 16 + n16) * 1032 + wave * 256 + ks * 32 + quad * 8];
        #pragma unroll
        for (int bt = 0; bt < 2; ++bt)
          #pragma unroll
          for (int g = 0; g < 4; ++g)
            acc[bt][g] = __builtin_amdgcn_mfma_f32_16x16x32_bf16(aT[bt], whhf[g][ks], acc[bt][g], 0, 0, 0);
      }
    }
    #pragma unroll
    for (int bt = 0; bt < 2; ++bt)
      #pragma unroll
      for (int g = 0; g < 4; ++g)
        #pragma unroll
        for (int r = 0; r < 4; ++r)
          part[wave][(bt * 16 + quad * 4 + r) * 69 + g * 16 + n16] = acc[bt][g][r];
    __syncthreads();

    // ---- 2. cross-wave reduce -> nonlinearity -> c,h
    {
      const int b = tid >> 3;
      const int jb = (tid & 7) * 2;
      #pragma unroll
      for (int u = 0; u < 2; ++u) {
        const int jj = jb + u;
        float G[4];
        #pragma unroll
        for (int g = 0; g < 4; ++g) {
          const int n = g * 16 + jj;
          G[g] = bias_l[n] + part[0][b * 69 + n] + part[1][b * 69 + n]
                           + part[2][b * 69 + n] + part[3][b * 69 + n];
        }
        const float ig = sigm(G[0]);
        const float fg = sigm(G[1]);
        const float gg = tanhf(G[2]);
        const float og = sigm(G[3]);
        float& c = u ? c1 : c0;
        c = fg * c + ig * gg;
        h_lds[b * 16 + jj] = og * tanhf(c);
      }
    }
    __syncthreads();

    // ---- 3. partial logits -> pf transposed [b][w][n] (agent write-through)
    {
      float* dst = pf + (size_t)buf * PF_STEP + (isF ? 0 : PF_F_SZ);
      for (int i = tid; i < NA * 32; i += WGS) {
        const int b = i / NA, n = i - b * NA;
        float v = 0.f;
        #pragma unroll
        for (int jj = 0; jj < 16; ++jj) v += h_lds[b * 16 + jj] * Wa_l[n * 17 + jj];
        __hip_atomic_store(&dst[(size_t)b * 64 * NA + wIdx * NA + n], v,
                           __ATOMIC_RELAXED, __HIP_MEMORY_SCOPE_AGENT);
      }
    }
    __syncthreads();   // all waves drain vmcnt before the counter bump
    if (tid == 0)
      __hip_atomic_fetch_add(isF ? cnt1F : cnt1R, 1u, __ATOMIC_RELEASE, __HIP_MEMORY_SCOPE_AGENT);

    // ---- 4. reducers: contiguous fan-in -> softmax -> items -> publish
    if (isRed) {
      if (tid == 0) {
        unsigned int* c1 = redF ? cnt1F : cnt1R;
        while (__hip_atomic_load(c1, __ATOMIC_RELAXED, __HIP_MEMORY_SCOPE_AGENT) <
               64u * (unsigned int)(s + 1))
          __builtin_amdgcn_s_sleep(1);
      }
      __syncthreads();
      __builtin_amdgcn_fence(__ATOMIC_ACQUIRE, "agent");
      const int NAr = redF ? NF_ : NR_;
      const float* src = pf + (size_t)buf * PF_STEP + (redF ? 0 : PF_F_SZ)
                            + (size_t)redB * 64 * NAr;
      float* stage = &part[0][0];
      const int nf4 = (64 * NAr) >> 2;    // 800 (F) / 560 (R)
      for (int i = tid; i < nf4; i += WGS) ((f4*)stage)[i] = ((const f4*)src)[i];
      __syncthreads();
      if (wave == 0) {
        const int n = (lane < NAr) ? lane : 0;
        float v = 0.f;
        #pragma unroll 16
        for (int w2 = 0; w2 < 64; ++w2) v += stage[w2 * NAr + n];
        const float* bA = redF ? bF_l : bR_l;
        float e = (lane < NAr) ? __expf(v + bA[n]) : 0.f;
        float ssum = e;
        #pragma unroll
        for (int off = 1; off < 64; off <<= 1) ssum += __shfl_xor(ssum, off, 64);
        const float a = e / ssum;
        if (lane < NAr) {
          arow[lane] = a;
          float* outA = redF ? out1 : out2;
          outA[((size_t)redB * S_ + s) * NAr + lane] = a;
        }
        if (lane < 32) {
          const float* WL = redF ? Fw_l : Rw_l;
          const float sc = redF ? sF : sR;
          float it = 0.f;
          for (int k = 0; k < NAr; ++k) it += arow[k] * WL[lane * NAr + k];
          it *= sc;
          __hip_atomic_store(&itBuf[((size_t)buf * 64 + (redF ? 0 : 32) + redB) * 32 + lane],
                             it, __ATOMIC_RELAXED, __HIP_MEMORY_SCOPE_AGENT);
        }
        if (lane == 0)
          __hip_atomic_fetch_add(cnt2, 1u, __ATOMIC_RELEASE, __HIP_MEMORY_SCOPE_AGENT);
      }
    }

    // ---- 5. overlap: next step's x-projection
    if (s + 1 < S_) xpart(s + 1);

    // ---- 6. wait for all 64 item rows (tid0 polls one dword; rest park at barrier)
    if (tid == 0) {
      while (__hip_atomic_load(cnt2, __ATOMIC_RELAXED, __HIP_MEMORY_SCOPE_AGENT) <
             64u * (unsigned int)(s + 1))
        __builtin_amdgcn_s_sleep(2);
    }
    __syncthreads();
    __builtin_amdgcn_fence(__ATOMIC_ACQUIRE, "agent");

    // ---- 7. read itemF/itemR (one contiguous 8 KB block), stage to LDS
    {
      const float* srcI = itBuf + (size_t)buf * 2048;
      for (int i = tid; i < 512; i += WGS) {
        f4 v = ((const f4*)srcI)[i];
        const int row = i >> 3, c4 = (i & 7) * 4;
        float* dstL = (row < 32) ? &itF_l[row * 33 + c4] : &itR_l[(row - 32) * 33 + c4];
        dstL[0] = v[0]; dstL[1] = v[1]; dstL[2] = v[2]; dstL[3] = v[3];
      }
    }
    __syncthreads();

    // ---- 8. T(s) = outer(itemF,itemR) -> bf16 LDS ; out0 by wg 32..63
    {
      const int b = tid & 31;
      const int ds0 = (tid >> 5) * 4;
      #pragma unroll
      for (int dsb = 0; dsb < 4; ++dsb) {
        const int ds = ds0 + dsb;
        const float fv = itF_l[b * 33 + ds];
        union { unsigned short us[32]; u4x v[4]; } tmp;
        #pragma unroll
        for (int dr = 0; dr < 32; ++dr) tmp.us[dr] = f2bf(fv * itR_l[b * 33 + dr]);
        #pragma unroll
        for (int q = 0; q < 4; ++q)
          *(u4x*)&T_lds[b * 1032 + ds * 32 + q * 8] = tmp.v[q];
      }
    }
    if (wg >= 32 && wg < 64) {
      const int b = wg - 32;
      const int ds = tid >> 3, dr0 = (tid & 7) * 4;
      f4 v;
      #pragma unroll
      for (int q = 0; q < 4; ++q) v[q] = itF_l[b * 33 + ds] * itR_l[b * 33 + dr0 + q];
      *(f4*)&out0[((size_t)b * S_ + s) * H_ + tid * 4] = v;
    }
    __syncthreads();
  }
}

// ------------------------------------------------------------- launcher
extern "C" void kernel_launch(void* const* d_in, const int* in_sizes, int n_in,
                              void* d_out, int out_size, void* d_ws, size_t ws_size,
                              hipStream_t stream) {
  (void)in_sizes; (void)n_in; (void)out_size;
  const float* x    = (const float*)d_in[0];
  const float* WihF = (const float*)d_in[1];
  const float* WhhF = (const float*)d_in[2];
  const float* bihF = (const float*)d_in[3];
  const float* bhhF = (const float*)d_in[4];
  const float* WihR = (const float*)d_in[5];
  const float* WhhR = (const float*)d_in[6];
  const float* bihR = (const float*)d_in[7];
  const float* bhhR = (const float*)d_in[8];
  const float* WaFw = (const float*)d_in[9];
  const float* WaFb = (const float*)d_in[10];
  const float* WaRw = (const float*)d_in[11];
  const float* WaRb = (const float*)d_in[12];
  const float* Fw   = (const float*)d_in[13];
  const float* Rw   = (const float*)d_in[14];
  const float* scF  = (const float*)d_in[15];
  const float* scR  = (const float*)d_in[16];

  unsigned char* ws = (unsigned char*)d_ws;
  unsigned short* xbf = (unsigned short*)(ws + XBF_OFF);
  const size_t need = (size_t)XBF_OFF + (size_t)B_ * S_ * D_ * 2;
  const int xmode = (ws_size >= need) ? 0 : 1;

  init_ws<<<8, 256, 0, stream>>>((unsigned int*)ws);
  if (xmode == 0)
    xcvt<<<2048, 256, 0, stream>>>(x, (unsigned int*)xbf, (B_ * S_ * D_) / 2);
  tpr_persist<<<NWG, WGS, 0, stream>>>(x, xbf, xmode,
      WihF, WhhF, bihF, bhhF, WihR, WhhR, bihR, bhhR,
      WaFw, WaFb, WaRw, WaRb, Fw, Rw, scF, scR,
      (float*)d_out, ws);
}

// Round 4
// 7570.819 us; speedup vs baseline: 2.4339x; 1.5625x over previous
//
#include <hip/hip_runtime.h>
#include <stdint.h>
#include <stddef.h>

// Problem constants
#define B_   32
#define S_   512
#define D_   768
#define H_   1024
#define NF_  50
#define NR_  35
#define NRP_ 36       // R logit row padded to even for b64 moves
#define NWG  128      // 64 WGs per cell, 16 hidden units each
#define WGS  256

// ws layout (bytes):
//   [0,128)     cntF     [128,256)  cntR      (RMW lines)
//   [256,384)   pubF     [384,512)  pubR      (poll lines, written once/step)
//   [512,640)   cnt2     [640,768)  pub2
//   [24576, +16384)  itBuf[2][64][32] floats (row = 128 B line)
//   [65536, ...)     pf partial logits [buf][cell][b][w][npad]
//   [1703936, ...)   xbf
#define PF_OFF    65536
#define XBF_OFF   1703936
#define PF_F_SZ   102400            // 32*64*50 floats
#define PF_STEP   176128            // + 32*64*36 floats

typedef __attribute__((ext_vector_type(8))) short sh8;   // 8 x bf16 MFMA operand
typedef __attribute__((ext_vector_type(4))) float f4;
typedef __attribute__((ext_vector_type(2))) float f2v;
typedef __attribute__((ext_vector_type(4))) unsigned int u4x;
typedef unsigned long long u64;

__device__ __forceinline__ unsigned short f2bf(float f) {
  unsigned int u = __float_as_uint(f);
  u += 0x7fffu + ((u >> 16) & 1u);
  return (unsigned short)(u >> 16);
}

__device__ __forceinline__ sh8 cvt8(const float* __restrict__ p) {
  f4 av = *(const f4*)p;
  f4 bv = *(const f4*)(p + 4);
  union { sh8 s; unsigned short us[8]; } r;
  r.us[0] = f2bf(av[0]); r.us[1] = f2bf(av[1]); r.us[2] = f2bf(av[2]); r.us[3] = f2bf(av[3]);
  r.us[4] = f2bf(bv[0]); r.us[5] = f2bf(bv[1]); r.us[6] = f2bf(bv[2]); r.us[7] = f2bf(bv[3]);
  return r.s;
}

__device__ __forceinline__ float sigm(float x) { return 1.f / (1.f + __expf(-x)); }

__device__ __forceinline__ u64 pack2(float a, float b) {
  return (u64)__float_as_uint(a) | ((u64)__float_as_uint(b) << 32);
}

// ---------------------------------------------------------------- init ws
__global__ void init_ws(unsigned int* __restrict__ flags) {
  const int t = blockIdx.x * blockDim.x + threadIdx.x;
  const int stride = gridDim.x * blockDim.x;
  for (int i = t; i < 6144; i += stride)
    __hip_atomic_store(&flags[i], 0u, __ATOMIC_RELAXED, __HIP_MEMORY_SCOPE_AGENT);
}

// ------------------------------------------------------- x fp32 -> bf16
__global__ void xcvt(const float* __restrict__ x, unsigned int* __restrict__ xb2, int npairs) {
  const int stride = gridDim.x * blockDim.x;
  for (int i = blockIdx.x * blockDim.x + threadIdx.x; i < npairs; i += stride) {
    f2v v = ((const f2v*)x)[i];
    xb2[i] = (unsigned int)f2bf(v[0]) | ((unsigned int)f2bf(v[1]) << 16);
  }
}

// ---------------------------------------------------------- persistent
__global__ __launch_bounds__(WGS, 1) void tpr_persist(
    const float* __restrict__ x, const unsigned short* __restrict__ xbf, int xmode,
    const float* __restrict__ WihF, const float* __restrict__ WhhF,
    const float* __restrict__ bihF, const float* __restrict__ bhhF,
    const float* __restrict__ WihR, const float* __restrict__ WhhR,
    const float* __restrict__ bihR, const float* __restrict__ bhhR,
    const float* __restrict__ WaFw, const float* __restrict__ WaFb,
    const float* __restrict__ WaRw, const float* __restrict__ WaRb,
    const float* __restrict__ Fw, const float* __restrict__ Rw,
    const float* __restrict__ scFp, const float* __restrict__ scRp,
    float* __restrict__ out0, unsigned char* __restrict__ ws)
{
  __shared__ __align__(16) unsigned short T_lds[32 * 1032];  // 66048 B
  __shared__ __align__(16) float part[4][32 * 69];           // 35328 B; reused as pf stage
  __shared__ float h_lds[32 * 16];
  __shared__ float itF_l[32 * 33];
  __shared__ float itR_l[32 * 33];
  __shared__ float Fw_l[32 * NF_];
  __shared__ float Rw_l[32 * NR_];
  __shared__ float Wa_l[NF_ * 17];
  __shared__ float arow[64];
  __shared__ float bias_l[64];
  __shared__ float bF_l[NF_];
  __shared__ float bR_l[NR_];

  const int wg   = blockIdx.x;
  const int tid  = threadIdx.x;
  const int wave = tid >> 6;
  const int lane = tid & 63;
  const int n16  = lane & 15;
  const int quad = lane >> 4;
  const bool isF = wg < 64;
  const int wIdx = wg & 63;            // writer index within cell
  const int j0   = wIdx * 16;
  const float* Wih = isF ? WihF : WihR;
  const float* Whh = isF ? WhhF : WhhR;
  const float* bih = isF ? bihF : bihR;
  const float* bhh = isF ? bhhF : bhhR;
  const float* Wa  = isF ? WaFw : WaRw;
  const int NA  = isF ? NF_ : NR_;
  const int NAp = isF ? NF_ : NRP_;    // padded row (even)
  const int npair = NAp >> 1;

  unsigned int* cntF = (unsigned int*)ws;
  unsigned int* cntR = (unsigned int*)(ws + 128);
  unsigned int* pubF = (unsigned int*)(ws + 256);
  unsigned int* pubR = (unsigned int*)(ws + 384);
  unsigned int* cnt2 = (unsigned int*)(ws + 512);
  unsigned int* pub2 = (unsigned int*)(ws + 640);
  float* itBuf = (float*)(ws + 24576);
  float* pf    = (float*)(ws + PF_OFF);

  // ---- resident weight fragments: wave owns K-quarter; 4 gate n-tiles
  sh8 whhf[4][8];
  sh8 wihf[4][6];
  #pragma unroll
  for (int g = 0; g < 4; ++g) {
    const int row = g * 1024 + j0 + n16;
    #pragma unroll
    for (int ks = 0; ks < 8; ++ks)
      whhf[g][ks] = cvt8(Whh + (size_t)row * H_ + wave * 256 + ks * 32 + quad * 8);
    #pragma unroll
    for (int ks = 0; ks < 6; ++ks)
      wihf[g][ks] = cvt8(Wih + (size_t)row * D_ + wave * 192 + ks * 32 + quad * 8);
  }

  if (tid < 64) {
    const int row = (tid >> 4) * 1024 + j0 + (tid & 15);
    bias_l[tid] = bih[row] + bhh[row];
  }
  for (int i = tid; i < NA * 16; i += WGS)
    Wa_l[(i >> 4) * 17 + (i & 15)] = Wa[(size_t)(i >> 4) * H_ + j0 + (i & 15)];
  for (int i = tid; i < 32 * NF_; i += WGS) Fw_l[i] = Fw[i];
  for (int i = tid; i < 32 * NR_; i += WGS) Rw_l[i] = Rw[i];
  if (tid < NF_) bF_l[tid] = WaFb[tid];
  if (tid < NR_) bR_l[tid] = WaRb[tid];
  {
    u4x z = {0u, 0u, 0u, 0u};
    for (int i = tid; i < (32 * 1032) / 8; i += WGS) ((u4x*)T_lds)[i] = z;
  }
  const float sF = scFp[0];
  const float sR = scRp[0];
  float c0 = 0.f, c1 = 0.f;

  f4 xacc[2][4];
  const f4 fz = {0.f, 0.f, 0.f, 0.f};

  auto xpart = [&](int sx) {
    #pragma unroll
    for (int bt = 0; bt < 2; ++bt)
      #pragma unroll
      for (int g = 0; g < 4; ++g) xacc[bt][g] = fz;
    #pragma unroll
    for (int ks = 0; ks < 6; ++ks) {
      sh8 xa[2];
      #pragma unroll
      for (int bt = 0; bt < 2; ++bt) {
        const size_t off = ((size_t)(bt * 16 + n16) * S_ + sx) * D_ + wave * 192 + ks * 32 + quad * 8;
        if (xmode == 0) {
          union { u4x u; sh8 s; } t;
          t.u = *(const u4x*)(xbf + off);
          xa[bt] = t.s;
        } else {
          xa[bt] = cvt8(x + off);
        }
      }
      #pragma unroll
      for (int bt = 0; bt < 2; ++bt)
        #pragma unroll
        for (int g = 0; g < 4; ++g)
          xacc[bt][g] = __builtin_amdgcn_mfma_f32_16x16x32_bf16(xa[bt], wihf[g][ks], xacc[bt][g], 0, 0, 0);
    }
  };

  xpart(0);
  __syncthreads();

  float* out1 = out0 + (size_t)B_ * S_ * H_;
  float* out2 = out1 + (size_t)B_ * S_ * NF_;

  // reducers: F on wg 0..31 (batch=wg), R on wg 96..127 (batch=wg-96)
  const bool isRed = (wg < 32) || (wg >= 96);
  const int  redB  = (wg < 32) ? wg : wg - 96;
  const bool redF  = (wg < 32);

  for (int s = 0; s < S_; ++s) {
    const int buf = s & 1;

    // ---- 1. gates = xacc + T(s-1) @ Whh^T
    f4 acc[2][4];
    #pragma unroll
    for (int bt = 0; bt < 2; ++bt)
      #pragma unroll
      for (int g = 0; g < 4; ++g) acc[bt][g] = xacc[bt][g];
    if (s > 0) {
      #pragma unroll
      for (int ks = 0; ks < 8; ++ks) {
        sh8 aT[2];
        #pragma unroll
        for (int bt = 0; bt < 2; ++bt)
          aT[bt] = *(const sh8*)&T_lds[(bt * 16 + n16) * 1032 + wave * 256 + ks * 32 + quad * 8];
        #pragma unroll
        for (int bt = 0; bt < 2; ++bt)
          #pragma unroll
          for (int g = 0; g < 4; ++g)
            acc[bt][g] = __builtin_amdgcn_mfma_f32_16x16x32_bf16(aT[bt], whhf[g][ks], acc[bt][g], 0, 0, 0);
      }
    }
    #pragma unroll
    for (int bt = 0; bt < 2; ++bt)
      #pragma unroll
      for (int g = 0; g < 4; ++g)
        #pragma unroll
        for (int r = 0; r < 4; ++r)
          part[wave][(bt * 16 + quad * 4 + r) * 69 + g * 16 + n16] = acc[bt][g][r];
    __syncthreads();

    // ---- 2. cross-wave reduce -> nonlinearity -> c,h
    {
      const int b = tid >> 3;
      const int jb = (tid & 7) * 2;
      #pragma unroll
      for (int u = 0; u < 2; ++u) {
        const int jj = jb + u;
        float G[4];
        #pragma unroll
        for (int g = 0; g < 4; ++g) {
          const int n = g * 16 + jj;
          G[g] = bias_l[n] + part[0][b * 69 + n] + part[1][b * 69 + n]
                           + part[2][b * 69 + n] + part[3][b * 69 + n];
        }
        const float ig = sigm(G[0]);
        const float fg = sigm(G[1]);
        const float gg = tanhf(G[2]);
        const float og = sigm(G[3]);
        float& c = u ? c1 : c0;
        c = fg * c + ig * gg;
        h_lds[b * 16 + jj] = og * tanhf(c);
      }
    }
    __syncthreads();

    // ---- 3. partial logits -> pf [b][w][npad] as b64 agent stores
    {
      u64* d64 = (u64*)(pf + (size_t)buf * PF_STEP + (isF ? 0 : PF_F_SZ));
      const int tot = 32 * npair;
      for (int i = tid; i < tot; i += WGS) {
        const int b = i / npair, k = i - b * npair;
        const int n0 = 2 * k, n1 = 2 * k + 1;
        float v0 = 0.f, v1 = 0.f;
        #pragma unroll
        for (int jj = 0; jj < 16; ++jj) v0 += h_lds[b * 16 + jj] * Wa_l[n0 * 17 + jj];
        if (n1 < NA) {
          #pragma unroll
          for (int jj = 0; jj < 16; ++jj) v1 += h_lds[b * 16 + jj] * Wa_l[n1 * 17 + jj];
        }
        __hip_atomic_store(&d64[(size_t)(b * 64 + wIdx) * npair + k], pack2(v0, v1),
                           __ATOMIC_RELAXED, __HIP_MEMORY_SCOPE_AGENT);
      }
    }
    __syncthreads();   // per-wave vmcnt(0) drain before the counter bump
    if (tid == 0) {
      const unsigned int old = __hip_atomic_fetch_add(isF ? cntF : cntR, 1u,
                                  __ATOMIC_RELAXED, __HIP_MEMORY_SCOPE_AGENT);
      if (old == 64u * (unsigned int)(s + 1) - 1u)
        __hip_atomic_store(isF ? pubF : pubR, (unsigned int)(s + 1),
                           __ATOMIC_RELAXED, __HIP_MEMORY_SCOPE_AGENT);
    }

    // ---- 4. reducers: b64 fan-in -> softmax -> items -> publish
    if (isRed) {
      if (tid == 0) {
        unsigned int* pb = redF ? pubF : pubR;
        while (__hip_atomic_load(pb, __ATOMIC_RELAXED, __HIP_MEMORY_SCOPE_AGENT) <
               (unsigned int)(s + 1))
          __builtin_amdgcn_s_sleep(1);
      }
      __syncthreads();
      const int NAr = redF ? NF_ : NR_;
      const int NApr = redF ? NF_ : NRP_;
      const u64* src64 = (const u64*)(pf + (size_t)buf * PF_STEP + (redF ? 0 : PF_F_SZ)
                                        + (size_t)redB * 64 * NApr);
      u64* st64 = (u64*)&part[0][0];
      const int n64 = (64 * NApr) >> 1;    // 1600 (F) / 1152 (R)
      for (int i = tid; i < n64; i += WGS)
        st64[i] = __hip_atomic_load(&src64[i], __ATOMIC_RELAXED, __HIP_MEMORY_SCOPE_AGENT);
      __syncthreads();
      if (wave == 0) {
        const float* stage = &part[0][0];
        const int n = (lane < NAr) ? lane : 0;
        float v = 0.f;
        #pragma unroll 16
        for (int w2 = 0; w2 < 64; ++w2) v += stage[w2 * NApr + n];
        const float* bA = redF ? bF_l : bR_l;
        float e = (lane < NAr) ? __expf(v + bA[n]) : 0.f;
        float ssum = e;
        #pragma unroll
        for (int off = 1; off < 64; off <<= 1) ssum += __shfl_xor(ssum, off, 64);
        const float a = e / ssum;
        if (lane < NAr) {
          arow[lane] = a;
          float* outA = redF ? out1 : out2;
          outA[((size_t)redB * S_ + s) * NAr + lane] = a;
        }
        if (lane < 32) {
          const float* WL = redF ? Fw_l : Rw_l;
          const float sc = redF ? sF : sR;
          float it = 0.f;
          for (int k = 0; k < NAr; ++k) it += arow[k] * WL[lane * NAr + k];
          it *= sc;
          __hip_atomic_store(&itBuf[((size_t)buf * 64 + (redF ? 0 : 32) + redB) * 32 + lane],
                             it, __ATOMIC_RELAXED, __HIP_MEMORY_SCOPE_AGENT);
        }
        if (lane == 0) {
          __asm__ __volatile__("s_waitcnt vmcnt(0)" ::: "memory");  // drain wave0's itBuf stores
          const unsigned int old = __hip_atomic_fetch_add(cnt2, 1u,
                                      __ATOMIC_RELAXED, __HIP_MEMORY_SCOPE_AGENT);
          if (old == 64u * (unsigned int)(s + 1) - 1u)
            __hip_atomic_store(pub2, (unsigned int)(s + 1),
                               __ATOMIC_RELAXED, __HIP_MEMORY_SCOPE_AGENT);
        }
      }
    }

    // ---- 5. overlap: next step's x-projection
    if (s + 1 < S_) xpart(s + 1);

    // ---- 6. wait for all 64 item rows (tid0 polls the read-only pub2 line)
    if (tid == 0) {
      while (__hip_atomic_load(pub2, __ATOMIC_RELAXED, __HIP_MEMORY_SCOPE_AGENT) <
             (unsigned int)(s + 1))
        __builtin_amdgcn_s_sleep(1);
    }
    __syncthreads();

    // ---- 7. read itemF/itemR via b64 atomic loads, stage to LDS
    {
      const u64* s64 = (const u64*)(itBuf + (size_t)buf * 2048);
      for (int i = tid; i < 1024; i += WGS) {
        const u64 p = __hip_atomic_load(&s64[i], __ATOMIC_RELAXED, __HIP_MEMORY_SCOPE_AGENT);
        const float lo = __uint_as_float((unsigned int)p);
        const float hi = __uint_as_float((unsigned int)(p >> 32));
        const int f0 = 2 * i;
        const int row = f0 >> 5, c4 = f0 & 31;
        if (row < 32) { itF_l[row * 33 + c4] = lo; itF_l[row * 33 + c4 + 1] = hi; }
        else          { itR_l[(row - 32) * 33 + c4] = lo; itR_l[(row - 32) * 33 + c4 + 1] = hi; }
      }
    }
    __syncthreads();

    // ---- 8. T(s) = outer(itemF,itemR) -> bf16 LDS ; out0 by wg 32..63
    {
      const int b = tid & 31;
      const int ds0 = (tid >> 5) * 4;
      #pragma unroll
      for (int dsb = 0; dsb < 4; ++dsb) {
        const int ds = ds0 + dsb;
        const float fv = itF_l[b * 33 + ds];
        union { unsigned short us[32]; u4x v[4]; } tmp;
        #pragma unroll
        for (int dr = 0; dr < 32; ++dr) tmp.us[dr] = f2bf(fv * itR_l[b * 33 + dr]);
        #pragma unroll
        for (int q = 0; q < 4; ++q)
          *(u4x*)&T_lds[b * 1032 + ds * 32 + q * 8] = tmp.v[q];
      }
    }
    if (wg >= 32 && wg < 64) {
      const int b = wg - 32;
      const int ds = tid >> 3, dr0 = (tid & 7) * 4;
      f4 v;
      #pragma unroll
      for (int q = 0; q < 4; ++q) v[q] = itF_l[b * 33 + ds] * itR_l[b * 33 + dr0 + q];
      *(f4*)&out0[((size_t)b * S_ + s) * H_ + tid * 4] = v;
    }
    __syncthreads();
  }
}

// ------------------------------------------------------------- launcher
extern "C" void kernel_launch(void* const* d_in, const int* in_sizes, int n_in,
                              void* d_out, int out_size, void* d_ws, size_t ws_size,
                              hipStream_t stream) {
  (void)in_sizes; (void)n_in; (void)out_size;
  const float* x    = (const float*)d_in[0];
  const float* WihF = (const float*)d_in[1];
  const float* WhhF = (const float*)d_in[2];
  const float* bihF = (const float*)d_in[3];
  const float* bhhF = (const float*)d_in[4];
  const float* WihR = (const float*)d_in[5];
  const float* WhhR = (const float*)d_in[6];
  const float* bihR = (const float*)d_in[7];
  const float* bhhR = (const float*)d_in[8];
  const float* WaFw = (const float*)d_in[9];
  const float* WaFb = (const float*)d_in[10];
  const float* WaRw = (const float*)d_in[11];
  const float* WaRb = (const float*)d_in[12];
  const float* Fw   = (const float*)d_in[13];
  const float* Rw   = (const float*)d_in[14];
  const float* scF  = (const float*)d_in[15];
  const float* scR  = (const float*)d_in[16];

  unsigned char* ws = (unsigned char*)d_ws;
  unsigned short* xbf = (unsigned short*)(ws + XBF_OFF);
  const size_t need = (size_t)XBF_OFF + (size_t)B_ * S_ * D_ * 2;
  const int xmode = (ws_size >= need) ? 0 : 1;

  init_ws<<<8, 256, 0, stream>>>((unsigned int*)ws);
  if (xmode == 0)
    xcvt<<<2048, 256, 0, stream>>>(x, (unsigned int*)xbf, (B_ * S_ * D_) / 2);
  tpr_persist<<<NWG, WGS, 0, stream>>>(x, xbf, xmode,
      WihF, WhhF, bihF, bhhF, WihR, WhhR, bihR, bhhR,
      WaFw, WaFb, WaRw, WaRb, Fw, Rw, scF, scR,
      (float*)d_out, ws);
}

// Round 5
// 6702.668 us; speedup vs baseline: 2.7491x; 1.1295x over previous
//
#include <hip/hip_runtime.h>
#include <stdint.h>
#include <stddef.h>

// Problem constants
#define B_   32
#define S_   512
#define D_   768
#define H_   1024
#define NF_  50
#define NR_  35
#define NRP_ 36       // R logit row padded to even for b64 moves
#define NWG  128      // 64 WGs per cell, 16 hidden units each
#define WGS  256

// ws layout (bytes):
//   [0,16384)        wtag[128] : dword at wg*32   (1 line per writer WG, monotone step tag)
//   [16384,24576)    rtag[64]  : dword at j*32    (1 line per reducer, monotone step tag)
//   [24576, +16384)  itBuf[2][64][32] floats (row = 128 B line)
//   [65536, ...)     pf partial logits [buf][cell][b][w][npad]
//   [1703936, ...)   xbf
#define PF_OFF    65536
#define XBF_OFF   1703936
#define PF_F_SZ   102400            // 32*64*50 floats
#define PF_STEP   176128            // + 32*64*36 floats

typedef __attribute__((ext_vector_type(8))) short sh8;   // 8 x bf16 MFMA operand
typedef __attribute__((ext_vector_type(4))) float f4;
typedef __attribute__((ext_vector_type(2))) float f2v;
typedef __attribute__((ext_vector_type(4))) unsigned int u4x;
typedef unsigned long long u64;

__device__ __forceinline__ unsigned short f2bf(float f) {
  unsigned int u = __float_as_uint(f);
  u += 0x7fffu + ((u >> 16) & 1u);
  return (unsigned short)(u >> 16);
}

__device__ __forceinline__ sh8 cvt8(const float* __restrict__ p) {
  f4 av = *(const f4*)p;
  f4 bv = *(const f4*)(p + 4);
  union { sh8 s; unsigned short us[8]; } r;
  r.us[0] = f2bf(av[0]); r.us[1] = f2bf(av[1]); r.us[2] = f2bf(av[2]); r.us[3] = f2bf(av[3]);
  r.us[4] = f2bf(bv[0]); r.us[5] = f2bf(bv[1]); r.us[6] = f2bf(bv[2]); r.us[7] = f2bf(bv[3]);
  return r.s;
}

__device__ __forceinline__ float sigm(float x) { return 1.f / (1.f + __expf(-x)); }

__device__ __forceinline__ u64 pack2(float a, float b) {
  return (u64)__float_as_uint(a) | ((u64)__float_as_uint(b) << 32);
}

// ---------------------------------------------------------------- init ws
__global__ void init_ws(unsigned int* __restrict__ flags) {
  const int t = blockIdx.x * blockDim.x + threadIdx.x;
  const int stride = gridDim.x * blockDim.x;
  for (int i = t; i < 6144; i += stride)   // 24576 B of tag lines
    __hip_atomic_store(&flags[i], 0u, __ATOMIC_RELAXED, __HIP_MEMORY_SCOPE_AGENT);
}

// ------------------------------------------------------- x fp32 -> bf16
__global__ void xcvt(const float* __restrict__ x, unsigned int* __restrict__ xb2, int npairs) {
  const int stride = gridDim.x * blockDim.x;
  for (int i = blockIdx.x * blockDim.x + threadIdx.x; i < npairs; i += stride) {
    f2v v = ((const f2v*)x)[i];
    xb2[i] = (unsigned int)f2bf(v[0]) | ((unsigned int)f2bf(v[1]) << 16);
  }
}

// ---------------------------------------------------------- persistent
__global__ __launch_bounds__(WGS, 1) void tpr_persist(
    const float* __restrict__ x, const unsigned short* __restrict__ xbf, int xmode,
    const float* __restrict__ WihF, const float* __restrict__ WhhF,
    const float* __restrict__ bihF, const float* __restrict__ bhhF,
    const float* __restrict__ WihR, const float* __restrict__ WhhR,
    const float* __restrict__ bihR, const float* __restrict__ bhhR,
    const float* __restrict__ WaFw, const float* __restrict__ WaFb,
    const float* __restrict__ WaRw, const float* __restrict__ WaRb,
    const float* __restrict__ Fw, const float* __restrict__ Rw,
    const float* __restrict__ scFp, const float* __restrict__ scRp,
    float* __restrict__ out0, unsigned char* __restrict__ ws)
{
  __shared__ __align__(16) unsigned short T_lds[32 * 1032];  // 66048 B
  __shared__ __align__(16) float part[4][32 * 69];           // 35328 B; reused as pf stage
  __shared__ float h_lds[32 * 16];
  __shared__ float itF_l[32 * 33];
  __shared__ float itR_l[32 * 33];
  __shared__ float Fw_l[32 * NF_];
  __shared__ float Rw_l[32 * NR_];
  __shared__ float Wa_l[NF_ * 17];
  __shared__ float red4[4][64];
  __shared__ float arow[64];
  __shared__ float bias_l[64];
  __shared__ float bF_l[NF_];
  __shared__ float bR_l[NR_];

  const int wg   = blockIdx.x;
  const int tid  = threadIdx.x;
  const int wave = tid >> 6;
  const int lane = tid & 63;
  const int n16  = lane & 15;
  const int quad = lane >> 4;
  const bool isF = wg < 64;
  const int wIdx = wg & 63;            // writer index within cell
  const int j0   = wIdx * 16;
  const float* Wih = isF ? WihF : WihR;
  const float* Whh = isF ? WhhF : WhhR;
  const float* bih = isF ? bihF : bihR;
  const float* bhh = isF ? bhhF : bhhR;
  const float* Wa  = isF ? WaFw : WaRw;
  const int NA  = isF ? NF_ : NR_;
  const int NAp = isF ? NF_ : NRP_;    // padded row (even)
  const int npair = NAp >> 1;

  unsigned int* wtag = (unsigned int*)ws;
  unsigned int* rtag = (unsigned int*)(ws + 16384);
  float* itBuf = (float*)(ws + 24576);
  float* pf    = (float*)(ws + PF_OFF);

  // ---- resident weight fragments: wave owns K-quarter; 4 gate n-tiles
  sh8 whhf[4][8];
  sh8 wihf[4][6];
  #pragma unroll
  for (int g = 0; g < 4; ++g) {
    const int row = g * 1024 + j0 + n16;
    #pragma unroll
    for (int ks = 0; ks < 8; ++ks)
      whhf[g][ks] = cvt8(Whh + (size_t)row * H_ + wave * 256 + ks * 32 + quad * 8);
    #pragma unroll
    for (int ks = 0; ks < 6; ++ks)
      wihf[g][ks] = cvt8(Wih + (size_t)row * D_ + wave * 192 + ks * 32 + quad * 8);
  }

  if (tid < 64) {
    const int row = (tid >> 4) * 1024 + j0 + (tid & 15);
    bias_l[tid] = bih[row] + bhh[row];
  }
  for (int i = tid; i < NA * 16; i += WGS)
    Wa_l[(i >> 4) * 17 + (i & 15)] = Wa[(size_t)(i >> 4) * H_ + j0 + (i & 15)];
  for (int i = tid; i < 32 * NF_; i += WGS) Fw_l[i] = Fw[i];
  for (int i = tid; i < 32 * NR_; i += WGS) Rw_l[i] = Rw[i];
  if (tid < NF_) bF_l[tid] = WaFb[tid];
  if (tid < NR_) bR_l[tid] = WaRb[tid];
  {
    u4x z = {0u, 0u, 0u, 0u};
    for (int i = tid; i < (32 * 1032) / 8; i += WGS) ((u4x*)T_lds)[i] = z;
  }
  const float sF = scFp[0];
  const float sR = scRp[0];
  float c0 = 0.f, c1 = 0.f;

  f4 xacc[2][4];
  const f4 fz = {0.f, 0.f, 0.f, 0.f};

  auto xpart = [&](int sx) {
    #pragma unroll
    for (int bt = 0; bt < 2; ++bt)
      #pragma unroll
      for (int g = 0; g < 4; ++g) xacc[bt][g] = fz;
    #pragma unroll
    for (int ks = 0; ks < 6; ++ks) {
      sh8 xa[2];
      #pragma unroll
      for (int bt = 0; bt < 2; ++bt) {
        const size_t off = ((size_t)(bt * 16 + n16) * S_ + sx) * D_ + wave * 192 + ks * 32 + quad * 8;
        if (xmode == 0) {
          union { u4x u; sh8 s; } t;
          t.u = *(const u4x*)(xbf + off);
          xa[bt] = t.s;
        } else {
          xa[bt] = cvt8(x + off);
        }
      }
      #pragma unroll
      for (int bt = 0; bt < 2; ++bt)
        #pragma unroll
        for (int g = 0; g < 4; ++g)
          xacc[bt][g] = __builtin_amdgcn_mfma_f32_16x16x32_bf16(xa[bt], wihf[g][ks], xacc[bt][g], 0, 0, 0);
    }
  };

  xpart(0);
  __syncthreads();

  float* out1 = out0 + (size_t)B_ * S_ * H_;
  float* out2 = out1 + (size_t)B_ * S_ * NF_;

  // reducers: F on wg 0..31 (batch=wg), R on wg 96..127 (batch=wg-96)
  const bool isRed = (wg < 32) || (wg >= 96);
  const int  redB  = (wg < 32) ? wg : wg - 96;
  const bool redF  = (wg < 32);
  const int  redJ  = (redF ? 0 : 32) + redB;     // itBuf row / rtag index

  for (int s = 0; s < S_; ++s) {
    const int buf = s & 1;
    const unsigned int stag = (unsigned int)(s + 1);

    // ---- 1. gates = xacc + T(s-1) @ Whh^T
    f4 acc[2][4];
    #pragma unroll
    for (int bt = 0; bt < 2; ++bt)
      #pragma unroll
      for (int g = 0; g < 4; ++g) acc[bt][g] = xacc[bt][g];
    if (s > 0) {
      #pragma unroll
      for (int ks = 0; ks < 8; ++ks) {
        sh8 aT[2];
        #pragma unroll
        for (int bt = 0; bt < 2; ++bt)
          aT[bt] = *(const sh8*)&T_lds[(bt * 16 + n16) * 1032 + wave * 256 + ks * 32 + quad * 8];
        #pragma unroll
        for (int bt = 0; bt < 2; ++bt)
          #pragma unroll
          for (int g = 0; g < 4; ++g)
            acc[bt][g] = __builtin_amdgcn_mfma_f32_16x16x32_bf16(aT[bt], whhf[g][ks], acc[bt][g], 0, 0, 0);
      }
    }
    #pragma unroll
    for (int bt = 0; bt < 2; ++bt)
      #pragma unroll
      for (int g = 0; g < 4; ++g)
        #pragma unroll
        for (int r = 0; r < 4; ++r)
          part[wave][(bt * 16 + quad * 4 + r) * 69 + g * 16 + n16] = acc[bt][g][r];
    __syncthreads();

    // ---- 2. cross-wave reduce -> nonlinearity -> c,h
    {
      const int b = tid >> 3;
      const int jb = (tid & 7) * 2;
      #pragma unroll
      for (int u = 0; u < 2; ++u) {
        const int jj = jb + u;
        float G[4];
        #pragma unroll
        for (int g = 0; g < 4; ++g) {
          const int n = g * 16 + jj;
          G[g] = bias_l[n] + part[0][b * 69 + n] + part[1][b * 69 + n]
                           + part[2][b * 69 + n] + part[3][b * 69 + n];
        }
        const float ig = sigm(G[0]);
        const float fg = sigm(G[1]);
        const float gg = tanhf(G[2]);
        const float og = sigm(G[3]);
        float& c = u ? c1 : c0;
        c = fg * c + ig * gg;
        h_lds[b * 16 + jj] = og * tanhf(c);
      }
    }
    __syncthreads();

    // ---- 3. partial logits -> pf [b][w][npad] as b64 agent stores
    {
      u64* d64 = (u64*)(pf + (size_t)buf * PF_STEP + (isF ? 0 : PF_F_SZ));
      const int tot = 32 * npair;
      for (int i = tid; i < tot; i += WGS) {
        const int b = i / npair, k = i - b * npair;
        const int n0 = 2 * k, n1 = 2 * k + 1;
        float v0 = 0.f, v1 = 0.f;
        #pragma unroll
        for (int jj = 0; jj < 16; ++jj) v0 += h_lds[b * 16 + jj] * Wa_l[n0 * 17 + jj];
        if (n1 < NA) {
          #pragma unroll
          for (int jj = 0; jj < 16; ++jj) v1 += h_lds[b * 16 + jj] * Wa_l[n1 * 17 + jj];
        }
        __hip_atomic_store(&d64[(size_t)(b * 64 + wIdx) * npair + k], pack2(v0, v1),
                           __ATOMIC_RELAXED, __HIP_MEMORY_SCOPE_AGENT);
      }
    }
    __syncthreads();   // per-wave vmcnt(0) drain: pf fully at LLC before tag
    if (tid == 0)
      __hip_atomic_store(&wtag[wg * 32], stag, __ATOMIC_RELAXED, __HIP_MEMORY_SCOPE_AGENT);

    // ---- 4. reducers: ballot-poll 64 writer tags -> b64 fan-in -> softmax -> items
    if (isRed) {
      const int cellbase = redF ? 0 : 64;
      if (wave == 0) {
        for (;;) {
          const unsigned int v = __hip_atomic_load(&wtag[(cellbase + lane) * 32],
                                                   __ATOMIC_RELAXED, __HIP_MEMORY_SCOPE_AGENT);
          if (__ballot(v >= stag) == ~0ull) break;
          __builtin_amdgcn_s_sleep(1);
        }
      }
      __syncthreads();
      const int NAr = redF ? NF_ : NR_;
      const int NApr = redF ? NF_ : NRP_;
      const u64* src64 = (const u64*)(pf + (size_t)buf * PF_STEP + (redF ? 0 : PF_F_SZ)
                                        + (size_t)redB * 64 * NApr);
      u64* st64 = (u64*)&part[0][0];
      const int n64 = (64 * NApr) >> 1;    // 1600 (F) / 1152 (R)
      for (int i = tid; i < n64; i += WGS)
        st64[i] = __hip_atomic_load(&src64[i], __ATOMIC_RELAXED, __HIP_MEMORY_SCOPE_AGENT);
      __syncthreads();
      // parallel partial reduce: wave w sums writer rows [w*16, w*16+16)
      {
        const float* stage = &part[0][0];
        const int n = (lane < NAr) ? lane : 0;
        float v = 0.f;
        #pragma unroll
        for (int w2 = 0; w2 < 16; ++w2) v += stage[(wave * 16 + w2) * NApr + n];
        red4[wave][lane] = v;
      }
      __syncthreads();
      if (wave == 0) {
        const int n = (lane < NAr) ? lane : 0;
        const float v = red4[0][lane] + red4[1][lane] + red4[2][lane] + red4[3][lane];
        const float* bA = redF ? bF_l : bR_l;
        float e = (lane < NAr) ? __expf(v + bA[n]) : 0.f;
        float ssum = e;
        #pragma unroll
        for (int off = 1; off < 64; off <<= 1) ssum += __shfl_xor(ssum, off, 64);
        const float a = e / ssum;
        if (lane < NAr) arow[lane] = a;
        if (lane < 32) {
          const float* WL = redF ? Fw_l : Rw_l;
          const float sc = redF ? sF : sR;
          float it = 0.f;
          for (int k = 0; k < NAr; ++k) it += arow[k] * WL[lane * NAr + k];
          it *= sc;
          __hip_atomic_store(&itBuf[((size_t)buf * 64 + redJ) * 32 + lane],
                             it, __ATOMIC_RELAXED, __HIP_MEMORY_SCOPE_AGENT);
        }
        if (lane == 0) {
          __asm__ __volatile__("s_waitcnt vmcnt(0)" ::: "memory");  // itBuf row at LLC
          __hip_atomic_store(&rtag[redJ * 32], stag, __ATOMIC_RELAXED, __HIP_MEMORY_SCOPE_AGENT);
        }
        // outputs AFTER the publish (off the critical path)
        if (lane < NAr) {
          float* outA = redF ? out1 : out2;
          outA[((size_t)redB * S_ + s) * NAr + lane] = a;
        }
      }
    }

    // ---- 5. overlap: next step's x-projection
    if (s + 1 < S_) xpart(s + 1);

    // ---- 6. wait for all 64 item rows (wave0 ballot-polls the 64 rtag lines)
    if (wave == 0) {
      for (;;) {
        const unsigned int v = __hip_atomic_load(&rtag[lane * 32],
                                                 __ATOMIC_RELAXED, __HIP_MEMORY_SCOPE_AGENT);
        if (__ballot(v >= stag) == ~0ull) break;
        __builtin_amdgcn_s_sleep(1);
      }
    }
    __syncthreads();

    // ---- 7. read itemF/itemR via b64 atomic loads, stage to LDS
    {
      const u64* s64 = (const u64*)(itBuf + (size_t)buf * 2048);
      for (int i = tid; i < 1024; i += WGS) {
        const u64 p = __hip_atomic_load(&s64[i], __ATOMIC_RELAXED, __HIP_MEMORY_SCOPE_AGENT);
        const float lo = __uint_as_float((unsigned int)p);
        const float hi = __uint_as_float((unsigned int)(p >> 32));
        const int f0 = 2 * i;
        const int row = f0 >> 5, c4 = f0 & 31;
        if (row < 32) { itF_l[row * 33 + c4] = lo; itF_l[row * 33 + c4 + 1] = hi; }
        else          { itR_l[(row - 32) * 33 + c4] = lo; itR_l[(row - 32) * 33 + c4 + 1] = hi; }
      }
    }
    __syncthreads();

    // ---- 8. T(s) = outer(itemF,itemR) -> bf16 LDS ; out0 by wg 32..63
    {
      const int b = tid & 31;
      const int ds0 = (tid >> 5) * 4;
      #pragma unroll
      for (int dsb = 0; dsb < 4; ++dsb) {
        const int ds = ds0 + dsb;
        const float fv = itF_l[b * 33 + ds];
        union { unsigned short us[32]; u4x v[4]; } tmp;
        #pragma unroll
        for (int dr = 0; dr < 32; ++dr) tmp.us[dr] = f2bf(fv * itR_l[b * 33 + dr]);
        #pragma unroll
        for (int q = 0; q < 4; ++q)
          *(u4x*)&T_lds[b * 1032 + ds * 32 + q * 8] = tmp.v[q];
      }
    }
    if (wg >= 32 && wg < 64) {
      const int b = wg - 32;
      const int ds = tid >> 3, dr0 = (tid & 7) * 4;
      f4 v;
      #pragma unroll
      for (int q = 0; q < 4; ++q) v[q] = itF_l[b * 33 + ds] * itR_l[b * 33 + dr0 + q];
      *(f4*)&out0[((size_t)b * S_ + s) * H_ + tid * 4] = v;
    }
    __syncthreads();
  }
}

// ------------------------------------------------------------- launcher
extern "C" void kernel_launch(void* const* d_in, const int* in_sizes, int n_in,
                              void* d_out, int out_size, void* d_ws, size_t ws_size,
                              hipStream_t stream) {
  (void)in_sizes; (void)n_in; (void)out_size;
  const float* x    = (const float*)d_in[0];
  const float* WihF = (const float*)d_in[1];
  const float* WhhF = (const float*)d_in[2];
  const float* bihF = (const float*)d_in[3];
  const float* bhhF = (const float*)d_in[4];
  const float* WihR = (const float*)d_in[5];
  const float* WhhR = (const float*)d_in[6];
  const float* bihR = (const float*)d_in[7];
  const float* bihR2= (const float*)d_in[8];
  const float* WaFw = (const float*)d_in[9];
  const float* WaFb = (const float*)d_in[10];
  const float* WaRw = (const float*)d_in[11];
  const float* WaRb = (const float*)d_in[12];
  const float* Fw   = (const float*)d_in[13];
  const float* Rw   = (const float*)d_in[14];
  const float* scF  = (const float*)d_in[15];
  const float* scR  = (const float*)d_in[16];

  unsigned char* ws = (unsigned char*)d_ws;
  unsigned short* xbf = (unsigned short*)(ws + XBF_OFF);
  const size_t need = (size_t)XBF_OFF + (size_t)B_ * S_ * D_ * 2;
  const int xmode = (ws_size >= need) ? 0 : 1;

  init_ws<<<8, 256, 0, stream>>>((unsigned int*)ws);
  if (xmode == 0)
    xcvt<<<2048, 256, 0, stream>>>(x, (unsigned int*)xbf, (B_ * S_ * D_) / 2);
  tpr_persist<<<NWG, WGS, 0, stream>>>(x, xbf, xmode,
      WihF, WhhF, bihF, bhhF, WihR, WhhR, bihR, bihR2,
      WaFw, WaFb, WaRw, WaRb, Fw, Rw, scF, scR,
      (float*)d_out, ws);
}